// Round 20
// baseline (213.890 us; speedup 1.0000x reference)
//
#include <hip/hip_runtime.h>
#include <hip/hip_bf16.h>
#include <math.h>

#define NF_IN 512
#define NF_OUT 256
#define HEADS 6
#define NCOLS (HEADS * NF_OUT)   // 1536
#define K2 (HEADS * NF_IN)       // 3072
#define SLOPE 0.2f

typedef __attribute__((ext_vector_type(8))) short short8;
typedef __attribute__((ext_vector_type(4))) float f32x4;

__device__ __forceinline__ float bf2f(unsigned short u) {
  unsigned int x = ((unsigned int)u) << 16;
  return __uint_as_float(x);
}
__device__ __forceinline__ unsigned short f2bf(float f) {
  unsigned int x = __float_as_uint(f);
  unsigned int lsb = (x >> 16) & 1u;
  x += 0x7fffu + lsb;
  return (unsigned short)(x >> 16);
}

__device__ __forceinline__ void gload_lds16(const void* g, void* l) {
  __builtin_amdgcn_global_load_lds(
      (const __attribute__((address_space(1))) void*)g,
      (__attribute__((address_space(3))) void*)l, 16, 0, 0);
}

// ---------------- merged: w_att (0..127) + W2t transpose (128..895) + edge count (896..) ----------------
__global__ __launch_bounds__(256) void wprep_kernel(
    const float* __restrict__ Wf, const float* __restrict__ Wc,
    const float* __restrict__ att_s, const float* __restrict__ att_d,
    float* __restrict__ wcomb, unsigned short* __restrict__ Wt2,
    const int* __restrict__ ei, int E, int Et, int* __restrict__ counts) {
  int bid = blockIdx.x;
  if (bid < 128) {
    int wid = threadIdx.x >> 6, lane = threadIdx.x & 63;
    int k = bid * 4 + wid;                // 0..511
    if (lane < 12) wcomb[lane * NF_IN + k] = Wc[k * 12 + lane];
#pragma unroll
    for (int h = 0; h < HEADS; ++h) {
      float4 w = *(const float4*)(Wf + (size_t)k * NCOLS + h * NF_OUT + lane * 4);
      float4 as = *(const float4*)(att_s + h * NF_OUT + lane * 4);
      float4 ad = *(const float4*)(att_d + h * NF_OUT + lane * 4);
      float s = w.x * as.x + w.y * as.y + w.z * as.z + w.w * as.w;
      float d = w.x * ad.x + w.y * ad.y + w.z * ad.z + w.w * ad.w;
#pragma unroll
      for (int off = 32; off; off >>= 1) {
        s += __shfl_xor(s, off, 64);
        d += __shfl_xor(d, off, 64);
      }
      if (lane == 0) {
        wcomb[(12 + h) * NF_IN + k] = s;
        wcomb[(18 + h) * NF_IN + k] = d;
      }
    }
  } else if (bid < 896) {
    __shared__ float tileS[32][33];
    int b2 = bid - 128;                   // 0..767
    int col0 = (b2 % 48) * 32;
    int k0 = (b2 / 48) * 32;
    int t = threadIdx.x;
    int tr = t >> 5;
    int tc = t & 31;
#pragma unroll
    for (int j = 0; j < 4; ++j)
      tileS[tr * 4 + j][tc] = Wf[(size_t)(k0 + tr * 4 + j) * NCOLS + col0 + tc];
    __syncthreads();
    int head = col0 >> 8;
    int cbase = col0 & 255;
#pragma unroll
    for (int j = 0; j < 4; ++j)
      Wt2[(size_t)(cbase + tr * 4 + j) * K2 + head * NF_IN + k0 + tc] =
          f2bf(tileS[tc][tr * 4 + j]);
  } else {
    int e = (bid - 896) * 256 + threadIdx.x;
    if (e < Et) {
      int d = (e < E) ? ei[E + e] : (e - E);
      atomicAdd(&counts[d], 1);
    }
  }
}

// ---------------- fused: data->bf16 + coord matvec + ALL scores ----------------
__global__ __launch_bounds__(256) void prep_data_kernel(
    const float* __restrict__ data, const float* __restrict__ wcomb,
    const float* __restrict__ att_src_c, const float* __restrict__ att_dst_c,
    unsigned short* __restrict__ data_bf, float* __restrict__ xp,
    float* __restrict__ asc, float* __restrict__ adc,
    float* __restrict__ asf, float* __restrict__ adf, int n_nodes) {
  __shared__ __align__(16) unsigned short Wb[24 * NF_IN];  // 24 KB
  int t = threadIdx.x;
#pragma unroll
  for (int i = 0; i < 3; ++i) {
    int c = i * 256 + t;
    const float* src = wcomb + c * 16;
    float4 a = *(const float4*)(src);
    float4 b = *(const float4*)(src + 4);
    float4 cc = *(const float4*)(src + 8);
    float4 d = *(const float4*)(src + 12);
    ushort4 u0, u1, u2, u3;
    u0.x = f2bf(a.x); u0.y = f2bf(a.y); u0.z = f2bf(a.z); u0.w = f2bf(a.w);
    u1.x = f2bf(b.x); u1.y = f2bf(b.y); u1.z = f2bf(b.z); u1.w = f2bf(b.w);
    u2.x = f2bf(cc.x); u2.y = f2bf(cc.y); u2.z = f2bf(cc.z); u2.w = f2bf(cc.w);
    u3.x = f2bf(d.x); u3.y = f2bf(d.y); u3.z = f2bf(d.z); u3.w = f2bf(d.w);
    *(ushort4*)(Wb + c * 16) = u0;
    *(ushort4*)(Wb + c * 16 + 4) = u1;
    *(ushort4*)(Wb + c * 16 + 8) = u2;
    *(ushort4*)(Wb + c * 16 + 12) = u3;
  }
  __syncthreads();
  int lane = t & 63;
  int gw = blockIdx.x * 4 + (t >> 6);
  int nw = gridDim.x * 4;
  for (int n = gw; n < n_nodes; n += nw) {
    const float* row = data + (size_t)n * NF_IN + lane * 8;
    float x[8];
    *(float4*)(x) = *(const float4*)(row);
    *(float4*)(x + 4) = *(const float4*)(row + 4);
    ushort4 b0, b1;
    b0.x = f2bf(x[0]); b0.y = f2bf(x[1]); b0.z = f2bf(x[2]); b0.w = f2bf(x[3]);
    b1.x = f2bf(x[4]); b1.y = f2bf(x[5]); b1.z = f2bf(x[6]); b1.w = f2bf(x[7]);
    unsigned short* db = data_bf + (size_t)n * NF_IN + lane * 8;
    *(ushort4*)(db) = b0;
    *(ushort4*)(db + 4) = b1;
    float acc[24];
#pragma unroll
    for (int o = 0; o < 24; ++o) {
      short8 w = *(const short8*)(Wb + o * NF_IN + lane * 8);
      float a = 0.f;
#pragma unroll
      for (int j = 0; j < 8; ++j) a += x[j] * bf2f((unsigned short)w[j]);
      acc[o] = a;
    }
#pragma unroll
    for (int o = 0; o < 24; ++o) {
#pragma unroll
      for (int off = 32; off; off >>= 1) acc[o] += __shfl_xor(acc[o], off, 64);
    }
    if (lane == 0) {
      float* xr = xp + (size_t)n * 12;
#pragma unroll
      for (int o = 0; o < 12; ++o) xr[o] = acc[o];
#pragma unroll
      for (int h = 0; h < HEADS; ++h) {
        asc[n * HEADS + h] = acc[2 * h] * att_src_c[2 * h] + acc[2 * h + 1] * att_src_c[2 * h + 1];
        adc[n * HEADS + h] = acc[2 * h] * att_dst_c[2 * h] + acc[2 * h + 1] * att_dst_c[2 * h + 1];
        asf[n * HEADS + h] = acc[12 + h];
        adf[n * HEADS + h] = acc[18 + h];
      }
    }
  }
}

// ---------------- fast single-block exclusive scan -> indptr ----------------
__global__ __launch_bounds__(1024) void scan_kernel(const int* __restrict__ counts,
                                                    int* __restrict__ indptr, int n) {
  __shared__ int wsum[16];
  const int CH = (n + 1023) >> 10;
  int t = threadIdx.x, lane = t & 63, w = t >> 6;
  int base = t * CH;
  int run = 0;
  for (int i = 0; i < CH; ++i) {
    int idx = base + i;
    run += (idx < n) ? counts[idx] : 0;
  }
  int tot = run;
#pragma unroll
  for (int off = 1; off < 64; off <<= 1) {
    int x = __shfl_up(tot, off, 64);
    if (lane >= off) tot += x;
  }
  if (lane == 63) wsum[w] = tot;
  __syncthreads();
  if (t == 0) {
    int s = 0;
#pragma unroll
    for (int i = 0; i < 16; ++i) { int x = wsum[i]; wsum[i] = s; s += x; }
  }
  __syncthreads();
  int run2 = wsum[w] + (tot - run);
  if (t == 0) indptr[0] = 0;
  for (int i = 0; i < CH; ++i) {
    int idx = base + i;
    if (idx < n) {
      run2 += counts[idx];
      indptr[idx + 1] = run2;
    }
  }
}

// ---------------- scatter to CSR ----------------
__global__ void scatter_kernel(const int* __restrict__ ei, int E, int Et,
                               const int* __restrict__ indptr, int* __restrict__ fill,
                               int* __restrict__ csr_src) {
  int e = blockIdx.x * blockDim.x + threadIdx.x;
  if (e >= Et) return;
  int s, d;
  if (e < E) { s = ei[e]; d = ei[E + e]; } else { s = d = e - E; }
  int pos = indptr[d] + atomicAdd(&fill[d], 1);
  csr_src[pos] = s;
}

// ---------------- coord-only softmax + coord aggregation + boundary ----------------
__global__ __launch_bounds__(256) void softmax_coord_kernel(
    const float* __restrict__ asc, const float* __restrict__ adc,
    const int* __restrict__ indptr, const int* __restrict__ csr_src,
    const float* __restrict__ xpc, const float* __restrict__ b_coord,
    const float* __restrict__ data, float* __restrict__ out_coord, int n_nodes) {
  int gid = blockIdx.x * blockDim.x + threadIdx.x;
  int n = gid >> 3;
  int h = gid & 7;
  bool act = (n < n_nodes) && (h < HEADS);
  int e0 = 0, e1 = 0;
  float adC = 0.f;
  if (act) {
    e0 = indptr[n];
    e1 = indptr[n + 1];
    adC = adc[n * HEADS + h];
  }
  float sC = 0.f, c0 = 0.f, c1 = 0.f;
  for (int p = e0; p < e1; ++p) {
    int s = csr_src[p];
    float vC = asc[s * HEADS + h] + adC;
    vC = (vC >= 0.f) ? vC : SLOPE * vC;
    float eC = __expf(vC);
    sC += eC;
    c0 += eC * xpc[(size_t)s * 12 + 2 * h];
    c1 += eC * xpc[(size_t)s * 12 + 2 * h + 1];
  }
  float iC = (1.f / (sC + 1e-16f)) * (1.f / HEADS);
  c0 *= iC;
  c1 *= iC;
#pragma unroll
  for (int off = 1; off < 8; off <<= 1) {
    c0 += __shfl_xor(c0, off, 8);
    c1 += __shfl_xor(c1, off, 8);
  }
  if (h == 0 && n < n_nodes) {
    c0 += b_coord[0];
    c1 += b_coord[1];
    float d0 = data[(size_t)n * NF_IN + 0];
    float d1 = data[(size_t)n * NF_IN + 1];
    if (d0 == 1.f) c0 = 1.f;
    if (d0 == 0.f) c0 = 0.f;
    if (d1 == 0.f) c1 = 0.f;
    if (d1 == 1.f) c1 = 1.f;
    out_coord[(size_t)n * 2 + 0] = c0;
    out_coord[(size_t)n * 2 + 1] = c1;
  }
}

// ---------------- fused softmax + aggregation: 2 waves/node, 3 heads each ----------------
// Computes eF = exp(leaky(asf[s]+adf[n])) inline (VALU hidden under gather
// latency), accumulates acc += eF*x and sF += eF, stores acc/sF. No coef_f
// or inv_f buffers needed.
__global__ __launch_bounds__(256) void agg_data_kernel(
    const unsigned short* __restrict__ xb, const float* __restrict__ asf,
    const float* __restrict__ adf, const int* __restrict__ indptr,
    const int* __restrict__ csr_src, unsigned short* __restrict__ AGG, int n_nodes) {
  int lane = threadIdx.x & 63;
  int gw = blockIdx.x * 4 + (threadIdx.x >> 6);
  int half = gw & 1;
  int h0 = half * 3;
  int nstep = (gridDim.x * 4) >> 1;
  const unsigned short* xbl = xb + lane * 8;

  for (int n = gw >> 1; n < n_nodes; n += nstep) {
    int e0 = indptr[n], e1 = indptr[n + 1];
    float adv[3];
#pragma unroll
    for (int j = 0; j < 3; ++j) adv[j] = adf[n * HEADS + h0 + j];
    float acc[3][8];
    float sF[3] = {0.f, 0.f, 0.f};
#pragma unroll
    for (int j = 0; j < 3; ++j)
#pragma unroll
      for (int i = 0; i < 8; ++i) acc[j][i] = 0.f;

    int p = e0;
    for (; p + 4 <= e1; p += 4) {
      int s0 = csr_src[p], s1 = csr_src[p + 1], s2 = csr_src[p + 2], s3 = csr_src[p + 3];
      short8 v0 = *(const short8*)(xbl + (size_t)s0 * NF_IN);
      short8 v1 = *(const short8*)(xbl + (size_t)s1 * NF_IN);
      short8 v2 = *(const short8*)(xbl + (size_t)s2 * NF_IN);
      short8 v3 = *(const short8*)(xbl + (size_t)s3 * NF_IN);
      float cf[4][3];
#pragma unroll
      for (int j = 0; j < 3; ++j) {
        cf[0][j] = asf[s0 * HEADS + h0 + j];
        cf[1][j] = asf[s1 * HEADS + h0 + j];
        cf[2][j] = asf[s2 * HEADS + h0 + j];
        cf[3][j] = asf[s3 * HEADS + h0 + j];
      }
#pragma unroll
      for (int e = 0; e < 4; ++e)
#pragma unroll
        for (int j = 0; j < 3; ++j) {
          float v = cf[e][j] + adv[j];
          v = (v >= 0.f) ? v : SLOPE * v;
          float ex = __expf(v);
          cf[e][j] = ex;
          sF[j] += ex;
        }
      float f[8];
#pragma unroll
      for (int i = 0; i < 8; ++i) f[i] = bf2f((unsigned short)v0[i]);
#pragma unroll
      for (int j = 0; j < 3; ++j)
#pragma unroll
        for (int i = 0; i < 8; ++i) acc[j][i] += cf[0][j] * f[i];
#pragma unroll
      for (int i = 0; i < 8; ++i) f[i] = bf2f((unsigned short)v1[i]);
#pragma unroll
      for (int j = 0; j < 3; ++j)
#pragma unroll
        for (int i = 0; i < 8; ++i) acc[j][i] += cf[1][j] * f[i];
#pragma unroll
      for (int i = 0; i < 8; ++i) f[i] = bf2f((unsigned short)v2[i]);
#pragma unroll
      for (int j = 0; j < 3; ++j)
#pragma unroll
        for (int i = 0; i < 8; ++i) acc[j][i] += cf[2][j] * f[i];
#pragma unroll
      for (int i = 0; i < 8; ++i) f[i] = bf2f((unsigned short)v3[i]);
#pragma unroll
      for (int j = 0; j < 3; ++j)
#pragma unroll
        for (int i = 0; i < 8; ++i) acc[j][i] += cf[3][j] * f[i];
    }
    for (; p < e1; ++p) {
      int s0 = csr_src[p];
      short8 v0 = *(const short8*)(xbl + (size_t)s0 * NF_IN);
      float f[8];
#pragma unroll
      for (int i = 0; i < 8; ++i) f[i] = bf2f((unsigned short)v0[i]);
#pragma unroll
      for (int j = 0; j < 3; ++j) {
        float v = asf[s0 * HEADS + h0 + j] + adv[j];
        v = (v >= 0.f) ? v : SLOPE * v;
        float ex = __expf(v);
        sF[j] += ex;
#pragma unroll
        for (int i = 0; i < 8; ++i) acc[j][i] += ex * f[i];
      }
    }
    unsigned short* og = AGG + (size_t)n * K2 + (size_t)h0 * NF_IN + lane * 8;
#pragma unroll
    for (int j = 0; j < 3; ++j) {
      float inv = 1.f / (sF[j] + 1e-16f);
      short8 w;
#pragma unroll
      for (int i = 0; i < 8; ++i) w[i] = (short)f2bf(acc[j][i] * inv);
      *(short8*)(og + j * NF_IN) = w;
    }
  }
}

// ---------------- GEMM2 (R12 config: 64x64, G2K=64, XCD-grouped, 2-barrier) ----------------
#define G2M 64
#define G2N 64
#define G2K 64
__global__ __launch_bounds__(256) void gemm2_kernel(
    const unsigned short* __restrict__ A, const unsigned short* __restrict__ Bt,
    const float* __restrict__ bias, float* __restrict__ outF, int M, int npan) {
  __shared__ __align__(16) unsigned short sA[G2M * G2K];  // 8 KB
  __shared__ __align__(16) unsigned short sB[G2N * G2K];  // 8 KB
  int b = blockIdx.x;
  int nwg = npan * 4;
  int q = nwg >> 3, r = nwg & 7;
  int xcd = b & 7, slot = b >> 3;
  int base = xcd * q + (xcd < r ? xcd : r);
  int nid = base + slot;
  int row0 = (nid >> 2) * G2M;
  int col0 = (nid & 3) * G2N;

  const int tid = threadIdx.x;
  const int wid = tid >> 6;
  const int lane = tid & 63;
  const int wr = (wid >> 1) * 32;
  const int wc = (wid & 1) * 32;

  f32x4 acc[2][2] = {};

  const int kseg = lane & 7;
  const int srow0 = (tid >> 3);
  const int swz0 = (kseg ^ (srow0 & 7)) * 8;
  const int swz1 = (kseg ^ ((srow0 + 32) & 7)) * 8;
  int ar0 = row0 + srow0; if (ar0 >= M) ar0 = M - 1;
  int ar1 = row0 + srow0 + 32; if (ar1 >= M) ar1 = M - 1;
  const unsigned short* gA0 = A + (size_t)ar0 * K2 + swz0;
  const unsigned short* gA1 = A + (size_t)ar1 * K2 + swz1;
  const unsigned short* gB0 = Bt + (size_t)(col0 + srow0) * K2 + swz0;
  const unsigned short* gB1 = Bt + (size_t)(col0 + srow0 + 32) * K2 + swz1;
  unsigned short* lA = sA + wid * 512;
  unsigned short* lB = sB + wid * 512;

  const int fr = lane & 15;
  const int g0 = lane >> 4;

  for (int k0 = 0; k0 < K2; k0 += G2K) {
    gload_lds16(gA0 + k0, lA);
    gload_lds16(gA1 + k0, lA + 2048);
    gload_lds16(gB0 + k0, lB);
    gload_lds16(gB1 + k0, lB + 2048);
    __syncthreads();
#pragma unroll
    for (int s = 0; s < 2; ++s) {
      short8 af[2], bfr[2];
#pragma unroll
      for (int m = 0; m < 2; ++m) {
        int rr = wr + m * 16 + fr;
        int gp = ((s * 4 + g0) ^ (rr & 7)) * 8;
        af[m] = *(const short8*)(sA + rr * G2K + gp);
      }
#pragma unroll
      for (int nn = 0; nn < 2; ++nn) {
        int rr = wc + nn * 16 + fr;
        int gp = ((s * 4 + g0) ^ (rr & 7)) * 8;
        bfr[nn] = *(const short8*)(sB + rr * G2K + gp);
      }
#pragma unroll
      for (int m = 0; m < 2; ++m)
#pragma unroll
        for (int nn = 0; nn < 2; ++nn)
          acc[m][nn] = __builtin_amdgcn_mfma_f32_16x16x32_bf16(af[m], bfr[nn],
                                                               acc[m][nn], 0, 0, 0);
    }
    __syncthreads();
  }

  const float selu_scale = 1.0507009873554805f;
  const float selu_alpha = 1.6732632423543772f;
  const int dcol = lane & 15;
  const int g4 = (lane >> 4) * 4;
#pragma unroll
  for (int m = 0; m < 2; ++m) {
#pragma unroll
    for (int i = 0; i < 4; ++i) {
      int rr = row0 + wr + m * 16 + g4 + i;
      if (rr < M) {
#pragma unroll
        for (int nn = 0; nn < 2; ++nn) {
          int c = col0 + wc + nn * 16 + dcol;
          float v = acc[m][nn][i] * (1.f / HEADS) + bias[c];
          v = (v > 0.f) ? selu_scale * v : selu_scale * selu_alpha * expm1f(v);
          outF[(size_t)rr * NF_OUT + c] = v;
        }
      }
    }
  }
}

extern "C" void kernel_launch(void* const* d_in, const int* in_sizes, int n_in,
                              void* d_out, int out_size, void* d_ws, size_t ws_size,
                              hipStream_t stream) {
  const float* data = (const float*)d_in[0];
  const int* ei = (const int*)d_in[1];
  const float* W_coord = (const float*)d_in[2];
  const float* att_src_coord = (const float*)d_in[3];
  const float* att_dst_coord = (const float*)d_in[4];
  const float* b_coord = (const float*)d_in[5];
  const float* W_feat = (const float*)d_in[6];
  const float* att_src_feat = (const float*)d_in[7];
  const float* att_dst_feat = (const float*)d_in[8];
  const float* b_feat = (const float*)d_in[9];
  float* out = (float*)d_out;

  const int n = in_sizes[0] / NF_IN;   // 20000
  const int E = in_sizes[1] / 2;       // 160000
  const int Et = E + n;

  char* ws = (char*)d_ws;
  size_t o = 0;
  unsigned short* AGG = (unsigned short*)(ws + o); o += (size_t)n * K2 * 2;       // 123 MB
  unsigned short* data_bf = (unsigned short*)(ws + o); o += (size_t)n * NF_IN * 2;
  unsigned short* w2t = (unsigned short*)(ws + o); o += (size_t)NF_OUT * K2 * 2;
  float* wcomb = (float*)(ws + o); o += (size_t)NF_IN * 24 * 4;
  float* xp_coord = (float*)(ws + o); o += (size_t)n * 12 * 4;
  float* asf = (float*)(ws + o); o += (size_t)n * HEADS * 4;
  float* adf = (float*)(ws + o); o += (size_t)n * HEADS * 4;
  float* asc = (float*)(ws + o); o += (size_t)n * HEADS * 4;
  float* adc = (float*)(ws + o); o += (size_t)n * HEADS * 4;
  int* counts = (int*)(ws + o); o += (size_t)n * 4;
  int* fill = (int*)(ws + o); o += (size_t)n * 4;
  int* indptr = (int*)(ws + o); o += ((size_t)n + 32) * 4;
  int* csr_src = (int*)(ws + o); o += (size_t)Et * 4;
  if (o > ws_size) return;  // workspace insufficient — fail loudly

  // 1. zero counts+fill via async memset
  hipMemsetAsync(counts, 0, (size_t)2 * n * 4, stream);
  // 2. merged w_att + W2t transpose + edge counting
  {
    int cblocks = (Et + 255) / 256;   // 704
    wprep_kernel<<<896 + cblocks, 256, 0, stream>>>(
        W_feat, W_coord, att_src_feat, att_dst_feat, wcomb, w2t, ei, E, Et, counts);
  }
  // 3. fused convert + coord rows + all scores
  prep_data_kernel<<<512, 256, 0, stream>>>(data, wcomb, att_src_coord,
                                            att_dst_coord, data_bf, xp_coord,
                                            asc, adc, asf, adf, n);
  // 4. scan
  scan_kernel<<<1, 1024, 0, stream>>>(counts, indptr, n);
  // 5. scatter
  scatter_kernel<<<(Et + 255) / 256, 256, 0, stream>>>(ei, E, Et, indptr, fill, csr_src);
  // 6. coord softmax + aggregation + boundary -> out[0 .. 2n)
  {
    int nb = (n * 8 + 255) / 256;
    softmax_coord_kernel<<<nb, 256, 0, stream>>>(asc, adc, indptr, csr_src,
                                                 xp_coord, b_coord, data, out, n);
  }
  // 7. fused feat softmax + aggregation -> AGG
  agg_data_kernel<<<2048, 256, 0, stream>>>(data_bf, asf, adf, indptr, csr_src,
                                            AGG, n);
  // 8. GEMM2 (R12 config) + mean/bias/SELU -> out[2n ..)
  {
    int npan = (n + G2M - 1) / G2M;  // 313
    gemm2_kernel<<<npan * 4, 256, 0, stream>>>(AGG, w2t, b_feat, out + (size_t)n * 2,
                                               n, npan);
  }
}

// Round 21
// 208.759 us; speedup vs baseline: 1.0246x; 1.0246x over previous
//
#include <hip/hip_runtime.h>
#include <hip/hip_bf16.h>
#include <math.h>

#define NF_IN 512
#define NF_OUT 256
#define HEADS 6
#define NCOLS (HEADS * NF_OUT)   // 1536
#define K2 (HEADS * NF_IN)       // 3072
#define SLOPE 0.2f

typedef __attribute__((ext_vector_type(8))) short short8;
typedef __attribute__((ext_vector_type(4))) float f32x4;

__device__ __forceinline__ float bf2f(unsigned short u) {
  unsigned int x = ((unsigned int)u) << 16;
  return __uint_as_float(x);
}
__device__ __forceinline__ unsigned short f2bf(float f) {
  unsigned int x = __float_as_uint(f);
  unsigned int lsb = (x >> 16) & 1u;
  x += 0x7fffu + lsb;
  return (unsigned short)(x >> 16);
}

__device__ __forceinline__ void gload_lds16(const void* g, void* l) {
  __builtin_amdgcn_global_load_lds(
      (const __attribute__((address_space(1))) void*)g,
      (__attribute__((address_space(3))) void*)l, 16, 0, 0);
}

// ---------------- merged: w_att (0..127) + W2t transpose (128..895) + edge count (896..) ----------------
__global__ __launch_bounds__(256) void wprep_kernel(
    const float* __restrict__ Wf, const float* __restrict__ Wc,
    const float* __restrict__ att_s, const float* __restrict__ att_d,
    float* __restrict__ wcomb, unsigned short* __restrict__ Wt2,
    const int* __restrict__ ei, int E, int Et, int* __restrict__ counts) {
  int bid = blockIdx.x;
  if (bid < 128) {
    int wid = threadIdx.x >> 6, lane = threadIdx.x & 63;
    int k = bid * 4 + wid;                // 0..511
    if (lane < 12) wcomb[lane * NF_IN + k] = Wc[k * 12 + lane];
#pragma unroll
    for (int h = 0; h < HEADS; ++h) {
      float4 w = *(const float4*)(Wf + (size_t)k * NCOLS + h * NF_OUT + lane * 4);
      float4 as = *(const float4*)(att_s + h * NF_OUT + lane * 4);
      float4 ad = *(const float4*)(att_d + h * NF_OUT + lane * 4);
      float s = w.x * as.x + w.y * as.y + w.z * as.z + w.w * as.w;
      float d = w.x * ad.x + w.y * ad.y + w.z * ad.z + w.w * ad.w;
#pragma unroll
      for (int off = 32; off; off >>= 1) {
        s += __shfl_xor(s, off, 64);
        d += __shfl_xor(d, off, 64);
      }
      if (lane == 0) {
        wcomb[(12 + h) * NF_IN + k] = s;
        wcomb[(18 + h) * NF_IN + k] = d;
      }
    }
  } else if (bid < 896) {
    __shared__ float tileS[32][33];
    int b2 = bid - 128;                   // 0..767
    int col0 = (b2 % 48) * 32;
    int k0 = (b2 / 48) * 32;
    int t = threadIdx.x;
    int tr = t >> 5;
    int tc = t & 31;
#pragma unroll
    for (int j = 0; j < 4; ++j)
      tileS[tr * 4 + j][tc] = Wf[(size_t)(k0 + tr * 4 + j) * NCOLS + col0 + tc];
    __syncthreads();
    int head = col0 >> 8;
    int cbase = col0 & 255;
#pragma unroll
    for (int j = 0; j < 4; ++j)
      Wt2[(size_t)(cbase + tr * 4 + j) * K2 + head * NF_IN + k0 + tc] =
          f2bf(tileS[tc][tr * 4 + j]);
  } else {
    int e = (bid - 896) * 256 + threadIdx.x;
    if (e < Et) {
      int d = (e < E) ? ei[E + e] : (e - E);
      atomicAdd(&counts[d], 1);
    }
  }
}

// ---------------- fused: data->bf16 + coord matvec + ALL scores ----------------
__global__ __launch_bounds__(256) void prep_data_kernel(
    const float* __restrict__ data, const float* __restrict__ wcomb,
    const float* __restrict__ att_src_c, const float* __restrict__ att_dst_c,
    unsigned short* __restrict__ data_bf, float* __restrict__ xp,
    float* __restrict__ asc, float* __restrict__ adc,
    float* __restrict__ asf, float* __restrict__ adf, int n_nodes) {
  __shared__ __align__(16) unsigned short Wb[24 * NF_IN];  // 24 KB
  int t = threadIdx.x;
#pragma unroll
  for (int i = 0; i < 3; ++i) {
    int c = i * 256 + t;
    const float* src = wcomb + c * 16;
    float4 a = *(const float4*)(src);
    float4 b = *(const float4*)(src + 4);
    float4 cc = *(const float4*)(src + 8);
    float4 d = *(const float4*)(src + 12);
    ushort4 u0, u1, u2, u3;
    u0.x = f2bf(a.x); u0.y = f2bf(a.y); u0.z = f2bf(a.z); u0.w = f2bf(a.w);
    u1.x = f2bf(b.x); u1.y = f2bf(b.y); u1.z = f2bf(b.z); u1.w = f2bf(b.w);
    u2.x = f2bf(cc.x); u2.y = f2bf(cc.y); u2.z = f2bf(cc.z); u2.w = f2bf(cc.w);
    u3.x = f2bf(d.x); u3.y = f2bf(d.y); u3.z = f2bf(d.z); u3.w = f2bf(d.w);
    *(ushort4*)(Wb + c * 16) = u0;
    *(ushort4*)(Wb + c * 16 + 4) = u1;
    *(ushort4*)(Wb + c * 16 + 8) = u2;
    *(ushort4*)(Wb + c * 16 + 12) = u3;
  }
  __syncthreads();
  int lane = t & 63;
  int gw = blockIdx.x * 4 + (t >> 6);
  int nw = gridDim.x * 4;
  for (int n = gw; n < n_nodes; n += nw) {
    const float* row = data + (size_t)n * NF_IN + lane * 8;
    float x[8];
    *(float4*)(x) = *(const float4*)(row);
    *(float4*)(x + 4) = *(const float4*)(row + 4);
    ushort4 b0, b1;
    b0.x = f2bf(x[0]); b0.y = f2bf(x[1]); b0.z = f2bf(x[2]); b0.w = f2bf(x[3]);
    b1.x = f2bf(x[4]); b1.y = f2bf(x[5]); b1.z = f2bf(x[6]); b1.w = f2bf(x[7]);
    unsigned short* db = data_bf + (size_t)n * NF_IN + lane * 8;
    *(ushort4*)(db) = b0;
    *(ushort4*)(db + 4) = b1;
    float acc[24];
#pragma unroll
    for (int o = 0; o < 24; ++o) {
      short8 w = *(const short8*)(Wb + o * NF_IN + lane * 8);
      float a = 0.f;
#pragma unroll
      for (int j = 0; j < 8; ++j) a += x[j] * bf2f((unsigned short)w[j]);
      acc[o] = a;
    }
#pragma unroll
    for (int o = 0; o < 24; ++o) {
#pragma unroll
      for (int off = 32; off; off >>= 1) acc[o] += __shfl_xor(acc[o], off, 64);
    }
    if (lane == 0) {
      float* xr = xp + (size_t)n * 12;
#pragma unroll
      for (int o = 0; o < 12; ++o) xr[o] = acc[o];
#pragma unroll
      for (int h = 0; h < HEADS; ++h) {
        asc[n * HEADS + h] = acc[2 * h] * att_src_c[2 * h] + acc[2 * h + 1] * att_src_c[2 * h + 1];
        adc[n * HEADS + h] = acc[2 * h] * att_dst_c[2 * h] + acc[2 * h + 1] * att_dst_c[2 * h + 1];
        asf[n * HEADS + h] = acc[12 + h];
        adf[n * HEADS + h] = acc[18 + h];
      }
    }
  }
}

// ---------------- fast single-block exclusive scan -> indptr ----------------
__global__ __launch_bounds__(1024) void scan_kernel(const int* __restrict__ counts,
                                                    int* __restrict__ indptr, int n) {
  __shared__ int wsum[16];
  const int CH = (n + 1023) >> 10;
  int t = threadIdx.x, lane = t & 63, w = t >> 6;
  int base = t * CH;
  int run = 0;
  for (int i = 0; i < CH; ++i) {
    int idx = base + i;
    run += (idx < n) ? counts[idx] : 0;
  }
  int tot = run;
#pragma unroll
  for (int off = 1; off < 64; off <<= 1) {
    int x = __shfl_up(tot, off, 64);
    if (lane >= off) tot += x;
  }
  if (lane == 63) wsum[w] = tot;
  __syncthreads();
  if (t == 0) {
    int s = 0;
#pragma unroll
    for (int i = 0; i < 16; ++i) { int x = wsum[i]; wsum[i] = s; s += x; }
  }
  __syncthreads();
  int run2 = wsum[w] + (tot - run);
  if (t == 0) indptr[0] = 0;
  for (int i = 0; i < CH; ++i) {
    int idx = base + i;
    if (idx < n) {
      run2 += counts[idx];
      indptr[idx + 1] = run2;
    }
  }
}

// ---------------- scatter to CSR ----------------
__global__ void scatter_kernel(const int* __restrict__ ei, int E, int Et,
                               const int* __restrict__ indptr, int* __restrict__ fill,
                               int* __restrict__ csr_src) {
  int e = blockIdx.x * blockDim.x + threadIdx.x;
  if (e >= Et) return;
  int s, d;
  if (e < E) { s = ei[e]; d = ei[E + e]; } else { s = d = e - E; }
  int pos = indptr[d] + atomicAdd(&fill[d], 1);
  csr_src[pos] = s;
}

// ---------------- single-pass softmax + coord aggregation + boundary ----------------
__global__ __launch_bounds__(256) void softmax_coord_kernel(
    const float* __restrict__ asf, const float* __restrict__ adf,
    const float* __restrict__ asc, const float* __restrict__ adc,
    const int* __restrict__ indptr, const int* __restrict__ csr_src,
    const float* __restrict__ xpc, const float* __restrict__ b_coord,
    const float* __restrict__ data, float* __restrict__ coef_f,
    float* __restrict__ inv_f, float* __restrict__ out_coord, int n_nodes) {
  int gid = blockIdx.x * blockDim.x + threadIdx.x;
  int n = gid >> 3;
  int h = gid & 7;
  bool act = (n < n_nodes) && (h < HEADS);
  int e0 = 0, e1 = 0;
  float adF = 0.f, adC = 0.f;
  if (act) {
    e0 = indptr[n];
    e1 = indptr[n + 1];
    adF = adf[n * HEADS + h];
    adC = adc[n * HEADS + h];
  }
  float sF = 0.f, sC = 0.f, c0 = 0.f, c1 = 0.f;
  for (int p = e0; p < e1; ++p) {
    int s = csr_src[p];
    float vF = asf[s * HEADS + h] + adF;
    float vC = asc[s * HEADS + h] + adC;
    vF = (vF >= 0.f) ? vF : SLOPE * vF;
    vC = (vC >= 0.f) ? vC : SLOPE * vC;
    float eF = __expf(vF);
    float eC = __expf(vC);
    coef_f[(size_t)p * HEADS + h] = eF;
    sF += eF;
    sC += eC;
    c0 += eC * xpc[(size_t)s * 12 + 2 * h];
    c1 += eC * xpc[(size_t)s * 12 + 2 * h + 1];
  }
  if (act) inv_f[n * HEADS + h] = 1.f / (sF + 1e-16f);
  float iC = (1.f / (sC + 1e-16f)) * (1.f / HEADS);
  c0 *= iC;
  c1 *= iC;
#pragma unroll
  for (int off = 1; off < 8; off <<= 1) {
    c0 += __shfl_xor(c0, off, 8);
    c1 += __shfl_xor(c1, off, 8);
  }
  if (h == 0 && n < n_nodes) {
    c0 += b_coord[0];
    c1 += b_coord[1];
    float d0 = data[(size_t)n * NF_IN + 0];
    float d1 = data[(size_t)n * NF_IN + 1];
    if (d0 == 1.f) c0 = 1.f;
    if (d0 == 0.f) c0 = 0.f;
    if (d1 == 0.f) c1 = 0.f;
    if (d1 == 1.f) c1 = 1.f;
    out_coord[(size_t)n * 2 + 0] = c0;
    out_coord[(size_t)n * 2 + 1] = c1;
  }
}

// ---------------- pre-GEMM aggregation: 2 waves/node, 3 heads each ----------------
__global__ __launch_bounds__(256) void agg_data_kernel(
    const unsigned short* __restrict__ xb, const float* __restrict__ coef,
    const float* __restrict__ invf, const int* __restrict__ indptr,
    const int* __restrict__ csr_src, unsigned short* __restrict__ AGG, int n_nodes) {
  int lane = threadIdx.x & 63;
  int gw = blockIdx.x * 4 + (threadIdx.x >> 6);
  int half = gw & 1;
  int h0 = half * 3;
  int nstep = (gridDim.x * 4) >> 1;
  const unsigned short* xbl = xb + lane * 8;

  for (int n = gw >> 1; n < n_nodes; n += nstep) {
    int e0 = indptr[n], e1 = indptr[n + 1];
    float inv[3];
#pragma unroll
    for (int j = 0; j < 3; ++j) inv[j] = invf[n * HEADS + h0 + j];
    float acc[3][8];
#pragma unroll
    for (int j = 0; j < 3; ++j)
#pragma unroll
      for (int i = 0; i < 8; ++i) acc[j][i] = 0.f;

    int p = e0;
    for (; p + 4 <= e1; p += 4) {
      int s0 = csr_src[p], s1 = csr_src[p + 1], s2 = csr_src[p + 2], s3 = csr_src[p + 3];
      short8 v0 = *(const short8*)(xbl + (size_t)s0 * NF_IN);
      short8 v1 = *(const short8*)(xbl + (size_t)s1 * NF_IN);
      short8 v2 = *(const short8*)(xbl + (size_t)s2 * NF_IN);
      short8 v3 = *(const short8*)(xbl + (size_t)s3 * NF_IN);
      float cf[4][3];
#pragma unroll
      for (int e = 0; e < 4; ++e)
#pragma unroll
        for (int j = 0; j < 3; ++j) cf[e][j] = coef[(size_t)(p + e) * HEADS + h0 + j];
      float f[8];
#pragma unroll
      for (int i = 0; i < 8; ++i) f[i] = bf2f((unsigned short)v0[i]);
#pragma unroll
      for (int j = 0; j < 3; ++j)
#pragma unroll
        for (int i = 0; i < 8; ++i) acc[j][i] += cf[0][j] * f[i];
#pragma unroll
      for (int i = 0; i < 8; ++i) f[i] = bf2f((unsigned short)v1[i]);
#pragma unroll
      for (int j = 0; j < 3; ++j)
#pragma unroll
        for (int i = 0; i < 8; ++i) acc[j][i] += cf[1][j] * f[i];
#pragma unroll
      for (int i = 0; i < 8; ++i) f[i] = bf2f((unsigned short)v2[i]);
#pragma unroll
      for (int j = 0; j < 3; ++j)
#pragma unroll
        for (int i = 0; i < 8; ++i) acc[j][i] += cf[2][j] * f[i];
#pragma unroll
      for (int i = 0; i < 8; ++i) f[i] = bf2f((unsigned short)v3[i]);
#pragma unroll
      for (int j = 0; j < 3; ++j)
#pragma unroll
        for (int i = 0; i < 8; ++i) acc[j][i] += cf[3][j] * f[i];
    }
    for (; p < e1; ++p) {
      int s0 = csr_src[p];
      short8 v0 = *(const short8*)(xbl + (size_t)s0 * NF_IN);
      float f[8];
#pragma unroll
      for (int i = 0; i < 8; ++i) f[i] = bf2f((unsigned short)v0[i]);
#pragma unroll
      for (int j = 0; j < 3; ++j) {
        float c = coef[(size_t)p * HEADS + h0 + j];
#pragma unroll
        for (int i = 0; i < 8; ++i) acc[j][i] += c * f[i];
      }
    }
    unsigned short* og = AGG + (size_t)n * K2 + (size_t)h0 * NF_IN + lane * 8;
#pragma unroll
    for (int j = 0; j < 3; ++j) {
      short8 w;
#pragma unroll
      for (int i = 0; i < 8; ++i) w[i] = (short)f2bf(acc[j][i] * inv[j]);
      *(short8*)(og + j * NF_IN) = w;
    }
  }
}

// ---------------- GEMM2 (R12 config: 64x64, G2K=64, XCD-grouped, 2-barrier) ----------------
#define G2M 64
#define G2N 64
#define G2K 64
__global__ __launch_bounds__(256) void gemm2_kernel(
    const unsigned short* __restrict__ A, const unsigned short* __restrict__ Bt,
    const float* __restrict__ bias, float* __restrict__ outF, int M, int npan) {
  __shared__ __align__(16) unsigned short sA[G2M * G2K];  // 8 KB
  __shared__ __align__(16) unsigned short sB[G2N * G2K];  // 8 KB
  int b = blockIdx.x;
  int nwg = npan * 4;
  int q = nwg >> 3, r = nwg & 7;
  int xcd = b & 7, slot = b >> 3;
  int base = xcd * q + (xcd < r ? xcd : r);
  int nid = base + slot;
  int row0 = (nid >> 2) * G2M;
  int col0 = (nid & 3) * G2N;

  const int tid = threadIdx.x;
  const int wid = tid >> 6;
  const int lane = tid & 63;
  const int wr = (wid >> 1) * 32;
  const int wc = (wid & 1) * 32;

  f32x4 acc[2][2] = {};

  const int kseg = lane & 7;
  const int srow0 = (tid >> 3);
  const int swz0 = (kseg ^ (srow0 & 7)) * 8;
  const int swz1 = (kseg ^ ((srow0 + 32) & 7)) * 8;
  int ar0 = row0 + srow0; if (ar0 >= M) ar0 = M - 1;
  int ar1 = row0 + srow0 + 32; if (ar1 >= M) ar1 = M - 1;
  const unsigned short* gA0 = A + (size_t)ar0 * K2 + swz0;
  const unsigned short* gA1 = A + (size_t)ar1 * K2 + swz1;
  const unsigned short* gB0 = Bt + (size_t)(col0 + srow0) * K2 + swz0;
  const unsigned short* gB1 = Bt + (size_t)(col0 + srow0 + 32) * K2 + swz1;
  unsigned short* lA = sA + wid * 512;
  unsigned short* lB = sB + wid * 512;

  const int fr = lane & 15;
  const int g0 = lane >> 4;

  for (int k0 = 0; k0 < K2; k0 += G2K) {
    gload_lds16(gA0 + k0, lA);
    gload_lds16(gA1 + k0, lA + 2048);
    gload_lds16(gB0 + k0, lB);
    gload_lds16(gB1 + k0, lB + 2048);
    __syncthreads();
#pragma unroll
    for (int s = 0; s < 2; ++s) {
      short8 af[2], bfr[2];
#pragma unroll
      for (int m = 0; m < 2; ++m) {
        int rr = wr + m * 16 + fr;
        int gp = ((s * 4 + g0) ^ (rr & 7)) * 8;
        af[m] = *(const short8*)(sA + rr * G2K + gp);
      }
#pragma unroll
      for (int nn = 0; nn < 2; ++nn) {
        int rr = wc + nn * 16 + fr;
        int gp = ((s * 4 + g0) ^ (rr & 7)) * 8;
        bfr[nn] = *(const short8*)(sB + rr * G2K + gp);
      }
#pragma unroll
      for (int m = 0; m < 2; ++m)
#pragma unroll
        for (int nn = 0; nn < 2; ++nn)
          acc[m][nn] = __builtin_amdgcn_mfma_f32_16x16x32_bf16(af[m], bfr[nn],
                                                               acc[m][nn], 0, 0, 0);
    }
    __syncthreads();
  }

  const float selu_scale = 1.0507009873554805f;
  const float selu_alpha = 1.6732632423543772f;
  const int dcol = lane & 15;
  const int g4 = (lane >> 4) * 4;
#pragma unroll
  for (int m = 0; m < 2; ++m) {
#pragma unroll
    for (int i = 0; i < 4; ++i) {
      int rr = row0 + wr + m * 16 + g4 + i;
      if (rr < M) {
#pragma unroll
        for (int nn = 0; nn < 2; ++nn) {
          int c = col0 + wc + nn * 16 + dcol;
          float v = acc[m][nn][i] * (1.f / HEADS) + bias[c];
          v = (v > 0.f) ? selu_scale * v : selu_scale * selu_alpha * expm1f(v);
          outF[(size_t)rr * NF_OUT + c] = v;
        }
      }
    }
  }
}

extern "C" void kernel_launch(void* const* d_in, const int* in_sizes, int n_in,
                              void* d_out, int out_size, void* d_ws, size_t ws_size,
                              hipStream_t stream) {
  const float* data = (const float*)d_in[0];
  const int* ei = (const int*)d_in[1];
  const float* W_coord = (const float*)d_in[2];
  const float* att_src_coord = (const float*)d_in[3];
  const float* att_dst_coord = (const float*)d_in[4];
  const float* b_coord = (const float*)d_in[5];
  const float* W_feat = (const float*)d_in[6];
  const float* att_src_feat = (const float*)d_in[7];
  const float* att_dst_feat = (const float*)d_in[8];
  const float* b_feat = (const float*)d_in[9];
  float* out = (float*)d_out;

  const int n = in_sizes[0] / NF_IN;   // 20000
  const int E = in_sizes[1] / 2;       // 160000
  const int Et = E + n;

  char* ws = (char*)d_ws;
  size_t o = 0;
  unsigned short* AGG = (unsigned short*)(ws + o); o += (size_t)n * K2 * 2;       // 123 MB
  unsigned short* data_bf = (unsigned short*)(ws + o); o += (size_t)n * NF_IN * 2;
  unsigned short* w2t = (unsigned short*)(ws + o); o += (size_t)NF_OUT * K2 * 2;
  float* wcomb = (float*)(ws + o); o += (size_t)NF_IN * 24 * 4;
  float* xp_coord = (float*)(ws + o); o += (size_t)n * 12 * 4;
  float* asf = (float*)(ws + o); o += (size_t)n * HEADS * 4;
  float* adf = (float*)(ws + o); o += (size_t)n * HEADS * 4;
  float* asc = (float*)(ws + o); o += (size_t)n * HEADS * 4;
  float* adc = (float*)(ws + o); o += (size_t)n * HEADS * 4;
  float* inv_f = (float*)(ws + o); o += (size_t)n * HEADS * 4;
  int* counts = (int*)(ws + o); o += (size_t)n * 4;
  int* fill = (int*)(ws + o); o += (size_t)n * 4;
  int* indptr = (int*)(ws + o); o += ((size_t)n + 32) * 4;
  int* csr_src = (int*)(ws + o); o += (size_t)Et * 4;
  float* coef_f = (float*)(ws + o); o += (size_t)Et * HEADS * 4;
  if (o > ws_size) return;  // workspace insufficient — fail loudly

  // 1. zero counts+fill via async memset
  hipMemsetAsync(counts, 0, (size_t)2 * n * 4, stream);
  // 2. merged w_att + W2t transpose + edge counting
  {
    int cblocks = (Et + 255) / 256;   // 704
    wprep_kernel<<<896 + cblocks, 256, 0, stream>>>(
        W_feat, W_coord, att_src_feat, att_dst_feat, wcomb, w2t, ei, E, Et, counts);
  }
  // 3. fused convert + coord rows + all scores
  prep_data_kernel<<<512, 256, 0, stream>>>(data, wcomb, att_src_coord,
                                            att_dst_coord, data_bf, xp_coord,
                                            asc, adc, asf, adf, n);
  // 4. scan
  scan_kernel<<<1, 1024, 0, stream>>>(counts, indptr, n);
  // 5. scatter
  scatter_kernel<<<(Et + 255) / 256, 256, 0, stream>>>(ei, E, Et, indptr, fill, csr_src);
  // 6. single-pass softmax + coord aggregation + boundary -> out[0 .. 2n)
  {
    int nb = (n * 8 + 255) / 256;
    softmax_coord_kernel<<<nb, 256, 0, stream>>>(asf, adf, asc, adc, indptr, csr_src,
                                                 xp_coord, b_coord, data, coef_f, inv_f,
                                                 out, n);
  }
  // 7. pre-GEMM aggregation
  agg_data_kernel<<<2048, 256, 0, stream>>>(data_bf, coef_f, inv_f, indptr, csr_src,
                                            AGG, n);
  // 8. GEMM2 (R12 config) + mean/bias/SELU -> out[2n ..)
  {
    int npan = (n + G2M - 1) / G2M;  // 313
    gemm2_kernel<<<npan * 4, 256, 0, stream>>>(AGG, w2t, b_feat, out + (size_t)n * 2,
                                               n, npan);
  }
}